// Round 2
// baseline (3022.745 us; speedup 1.0000x reference)
//
#include <hip/hip_runtime.h>
#include <hip/hip_bf16.h>

#define T_SEQ 512
#define BATCH 16
#define EMB 768
#define HEADS 32
#define HDIM 24
#define ROWS (T_SEQ * BATCH)  /* 8192 */
#define SCALING 0.20412414523193154f /* 24^-0.5 */

// ---------------------------------------------------------------------------
// Fused QKV projection: X[8192,768] @ W^T + b for W in {Wq,Wk,Wv}.
// Output layout [bh = b*32+h][t][dd] so attention reads are contiguous.
// Tile: 64x64, BK=16, 256 threads, 4x4 micro-tile per thread.
// ---------------------------------------------------------------------------
__global__ __launch_bounds__(256)
void qkv_proj_kernel(const float* __restrict__ X,
                     const float* __restrict__ Wq, const float* __restrict__ Wk,
                     const float* __restrict__ Wv,
                     const float* __restrict__ bq, const float* __restrict__ bk,
                     const float* __restrict__ bv,
                     float* __restrict__ qo, float* __restrict__ ko,
                     float* __restrict__ vo)
{
    __shared__ float Xs[64][17];
    __shared__ __attribute__((aligned(16))) float Ws[16][68];

    const int tid = threadIdx.x;
    const int r0 = blockIdx.x * 64;
    const int nb = blockIdx.y;            // 0..35 -> (q|k|v) x 12 col-blocks
    const int which = nb / 12;
    const int n0 = (nb % 12) * 64;
    const float* W    = (which == 0) ? Wq : (which == 1) ? Wk : Wv;
    const float* bias = (which == 0) ? bq : (which == 1) ? bk : bv;
    float* out        = (which == 0) ? qo : (which == 1) ? ko : vo;

    const int lrow = tid >> 2;
    const int lcol = (tid & 3) << 2;
    const int tx = tid & 15;
    const int ty = tid >> 4;

    float acc[4][4] = {};

    for (int k0 = 0; k0 < EMB; k0 += 16) {
        const float4 xv = *(const float4*)(X + (size_t)(r0 + lrow) * EMB + k0 + lcol);
        const float4 wv = *(const float4*)(W + (size_t)(n0 + lrow) * EMB + k0 + lcol);
        Xs[lrow][lcol + 0] = xv.x; Xs[lrow][lcol + 1] = xv.y;
        Xs[lrow][lcol + 2] = xv.z; Xs[lrow][lcol + 3] = xv.w;
        Ws[lcol + 0][lrow] = wv.x; Ws[lcol + 1][lrow] = wv.y;
        Ws[lcol + 2][lrow] = wv.z; Ws[lcol + 3][lrow] = wv.w;
        __syncthreads();
#pragma unroll
        for (int kk = 0; kk < 16; ++kk) {
            const float4 b4 = *(const float4*)&Ws[kk][tx * 4];
            const float a0 = Xs[ty * 4 + 0][kk];
            const float a1 = Xs[ty * 4 + 1][kk];
            const float a2 = Xs[ty * 4 + 2][kk];
            const float a3 = Xs[ty * 4 + 3][kk];
            acc[0][0] += a0 * b4.x; acc[0][1] += a0 * b4.y; acc[0][2] += a0 * b4.z; acc[0][3] += a0 * b4.w;
            acc[1][0] += a1 * b4.x; acc[1][1] += a1 * b4.y; acc[1][2] += a1 * b4.z; acc[1][3] += a1 * b4.w;
            acc[2][0] += a2 * b4.x; acc[2][1] += a2 * b4.y; acc[2][2] += a2 * b4.z; acc[2][3] += a2 * b4.w;
            acc[3][0] += a3 * b4.x; acc[3][1] += a3 * b4.y; acc[3][2] += a3 * b4.z; acc[3][3] += a3 * b4.w;
        }
        __syncthreads();
    }

#pragma unroll
    for (int ii = 0; ii < 4; ++ii) {
        const int rr = r0 + ty * 4 + ii;
        const int t = rr >> 4;
        const int b = rr & 15;
#pragma unroll
        for (int jj = 0; jj < 4; ++jj) {
            const int nn = n0 + tx * 4 + jj;
            float c = acc[ii][jj] + bias[nn];
            if (which == 0) c *= SCALING;
            const int h = nn / HDIM;
            const int dd = nn - h * HDIM;
            out[((size_t)((b * HEADS + h) * T_SEQ + t)) * HDIM + dd] = c;
        }
    }
}

// ---------------------------------------------------------------------------
// Attention v2: block = (16 q-rows, one bh), 384 threads.
//  - K/V staged in one 128x28 LDS tile buffer, float4 coalesced loads
//  - bias read as float4 (coalesced), fused into score
//  - scores (16x512) in LDS stride 521 -> 16 rows hit 16 distinct banks
//  - PV: thread <-> (row, dim) exactly (16*24 = 384)
// Grid: (T/16, B*H) so consecutive blocks share K/V (L2 locality).
// ---------------------------------------------------------------------------
__global__ __launch_bounds__(384)
void attn_kernel(const float* __restrict__ qb, const float* __restrict__ kb,
                 const float* __restrict__ vb, const float* __restrict__ bias,
                 float* __restrict__ attn)
{
    const int t0 = blockIdx.x * 16;
    const int bh = blockIdx.y;            // b*32 + h
    const int tid = threadIdx.x;

    __shared__ float Qs[16][25];
    __shared__ float Ss[16][521];
    __shared__ __attribute__((aligned(16))) float Ts[128][28];
    __shared__ float red[16][17];
    __shared__ float rowm[16];
    __shared__ float rowl[16];

    const float* Kb = kb + (size_t)bh * T_SEQ * HDIM;
    const float* Vb = vb + (size_t)bh * T_SEQ * HDIM;
    const float* Bb = bias + (size_t)bh * T_SEQ * T_SEQ + (size_t)t0 * T_SEQ;

    // stage Q: 16*24 = 384 elements, one per thread
    {
        const int i = tid / HDIM, dd = tid - i * HDIM;
        Qs[i][dd] = qb[((size_t)bh * T_SEQ + t0 + i) * HDIM + dd];
    }
    __syncthreads();

    // ---- phase 1: scores = q.k + bias, K staged in 128-row tiles ----
    for (int tile = 0; tile < 4; ++tile) {
        for (int fv = tid; fv < 768; fv += 384) {        // 128*24/4 float4s
            const float4 kv = *(const float4*)(Kb + (size_t)tile * 3072 + (size_t)fv * 4);
            const int row = fv / 6;
            const int col = (fv - row * 6) * 4;
            *(float4*)&Ts[row][col] = kv;
        }
        __syncthreads();
        for (int f = tid; f < 512; f += 384) {           // 16 rows * 32 groups
            const int i = f >> 5;
            const int sl = (f & 31) * 4;
            const float4 bv = *(const float4*)(Bb + (size_t)i * T_SEQ + tile * 128 + sl);
            float d0 = 0.f, d1 = 0.f, d2 = 0.f, d3 = 0.f;
#pragma unroll
            for (int dd = 0; dd < HDIM; ++dd) {
                const float q = Qs[i][dd];
                d0 += q * Ts[sl + 0][dd];
                d1 += q * Ts[sl + 1][dd];
                d2 += q * Ts[sl + 2][dd];
                d3 += q * Ts[sl + 3][dd];
            }
            const int sg = tile * 128 + sl;
            Ss[i][sg + 0] = d0 + bv.x;
            Ss[i][sg + 1] = d1 + bv.y;
            Ss[i][sg + 2] = d2 + bv.z;
            Ss[i][sg + 3] = d3 + bv.w;
        }
        __syncthreads();
    }

    // ---- phase 2: softmax per row (first 256 threads, 16 per row) ----
    if (tid < 256) {
        const int i = tid >> 4;
        const int g = tid & 15;
        float m = -1e30f;
        for (int s = g; s < T_SEQ; s += 16) m = fmaxf(m, Ss[i][s]);
        red[i][g] = m;
    }
    __syncthreads();
    if (tid < 256 && (tid & 15) == 0) {
        const int i = tid >> 4;
        float mm = red[i][0];
#pragma unroll
        for (int j = 1; j < 16; ++j) mm = fmaxf(mm, red[i][j]);
        rowm[i] = mm;
    }
    __syncthreads();
    if (tid < 256) {
        const int i = tid >> 4;
        const int g = tid & 15;
        const float mrow = rowm[i];
        float l = 0.f;
        for (int s = g; s < T_SEQ; s += 16) {
            const float p = __expf(Ss[i][s] - mrow);
            Ss[i][s] = p;
            l += p;
        }
        red[i][g] = l;
    }
    __syncthreads();
    if (tid < 256 && (tid & 15) == 0) {
        const int i = tid >> 4;
        float ll = 0.f;
#pragma unroll
        for (int j = 0; j < 16; ++j) ll += red[i][j];
        rowl[i] = 1.f / ll;
    }

    // ---- phase 3: PV, V staged in the same tile buffer ----
    const int pi = tid / HDIM;
    const int pd = tid - pi * HDIM;
    float accv = 0.f;
    for (int tile = 0; tile < 4; ++tile) {
        __syncthreads();   // previous Ts consumers done (incl. softmax on tile 0)
        for (int fv = tid; fv < 768; fv += 384) {
            const float4 vv = *(const float4*)(Vb + (size_t)tile * 3072 + (size_t)fv * 4);
            const int row = fv / 6;
            const int col = (fv - row * 6) * 4;
            *(float4*)&Ts[row][col] = vv;
        }
        __syncthreads();
        const int sbase = tile * 128;
#pragma unroll 4
        for (int sl = 0; sl < 128; ++sl) {
            accv += Ss[pi][sbase + sl] * Ts[sl][pd];
        }
    }
    accv *= rowl[pi];
    const int b = bh >> 5;
    const int h = bh & 31;
    attn[((size_t)((t0 + pi) * BATCH + b)) * EMB + h * HDIM + pd] = accv;
}

// ---------------------------------------------------------------------------
// Output projection: attn[8192,768] @ Wo^T + bo -> out
// ---------------------------------------------------------------------------
__global__ __launch_bounds__(256)
void out_proj_kernel(const float* __restrict__ A, const float* __restrict__ Wo,
                     const float* __restrict__ bo, float* __restrict__ out)
{
    __shared__ float Xs[64][17];
    __shared__ __attribute__((aligned(16))) float Ws[16][68];

    const int tid = threadIdx.x;
    const int r0 = blockIdx.x * 64;
    const int n0 = blockIdx.y * 64;

    const int lrow = tid >> 2;
    const int lcol = (tid & 3) << 2;
    const int tx = tid & 15;
    const int ty = tid >> 4;

    float acc[4][4] = {};

    for (int k0 = 0; k0 < EMB; k0 += 16) {
        const float4 xv = *(const float4*)(A + (size_t)(r0 + lrow) * EMB + k0 + lcol);
        const float4 wv = *(const float4*)(Wo + (size_t)(n0 + lrow) * EMB + k0 + lcol);
        Xs[lrow][lcol + 0] = xv.x; Xs[lrow][lcol + 1] = xv.y;
        Xs[lrow][lcol + 2] = xv.z; Xs[lrow][lcol + 3] = xv.w;
        Ws[lcol + 0][lrow] = wv.x; Ws[lcol + 1][lrow] = wv.y;
        Ws[lcol + 2][lrow] = wv.z; Ws[lcol + 3][lrow] = wv.w;
        __syncthreads();
#pragma unroll
        for (int kk = 0; kk < 16; ++kk) {
            const float4 b4 = *(const float4*)&Ws[kk][tx * 4];
            const float a0 = Xs[ty * 4 + 0][kk];
            const float a1 = Xs[ty * 4 + 1][kk];
            const float a2 = Xs[ty * 4 + 2][kk];
            const float a3 = Xs[ty * 4 + 3][kk];
            acc[0][0] += a0 * b4.x; acc[0][1] += a0 * b4.y; acc[0][2] += a0 * b4.z; acc[0][3] += a0 * b4.w;
            acc[1][0] += a1 * b4.x; acc[1][1] += a1 * b4.y; acc[1][2] += a1 * b4.z; acc[1][3] += a1 * b4.w;
            acc[2][0] += a2 * b4.x; acc[2][1] += a2 * b4.y; acc[2][2] += a2 * b4.z; acc[2][3] += a2 * b4.w;
            acc[3][0] += a3 * b4.x; acc[3][1] += a3 * b4.y; acc[3][2] += a3 * b4.z; acc[3][3] += a3 * b4.w;
        }
        __syncthreads();
    }

#pragma unroll
    for (int ii = 0; ii < 4; ++ii) {
        const int rr = r0 + ty * 4 + ii;
#pragma unroll
        for (int jj = 0; jj < 4; ++jj) {
            const int nn = n0 + tx * 4 + jj;
            out[(size_t)rr * EMB + nn] = acc[ii][jj] + bo[nn];
        }
    }
}

extern "C" void kernel_launch(void* const* d_in, const int* in_sizes, int n_in,
                              void* d_out, int out_size, void* d_ws, size_t ws_size,
                              hipStream_t stream)
{
    const float* query = (const float*)d_in[0];
    const float* abias = (const float*)d_in[1];
    const float* Wq = (const float*)d_in[2];
    const float* bq = (const float*)d_in[3];
    const float* Wk = (const float*)d_in[4];
    const float* bk = (const float*)d_in[5];
    const float* Wv = (const float*)d_in[6];
    const float* bv = (const float*)d_in[7];
    const float* Wo = (const float*)d_in[8];
    const float* bo = (const float*)d_in[9];
    float* out = (float*)d_out;

    float* ws = (float*)d_ws;
    const size_t QKV_ELEMS = (size_t)BATCH * HEADS * T_SEQ * HDIM; // 6291456
    float* qb = ws;
    float* kb = ws + QKV_ELEMS;
    float* vb = ws + 2 * QKV_ELEMS;
    float* ab = ws + 3 * QKV_ELEMS;                                // [8192,768]

    dim3 gA(ROWS / 64, 36);
    qkv_proj_kernel<<<gA, 256, 0, stream>>>(query, Wq, Wk, Wv, bq, bk, bv, qb, kb, vb);

    dim3 gB(T_SEQ / 16, BATCH * HEADS);
    attn_kernel<<<gB, 384, 0, stream>>>(qb, kb, vb, abias, ab);

    dim3 gC(ROWS / 64, EMB / 64);
    out_proj_kernel<<<gC, 256, 0, stream>>>(ab, Wo, bo, out);
}